// Round 5
// baseline (192.381 us; speedup 1.0000x reference)
//
#include <hip/hip_runtime.h>
#include <hip/hip_bf16.h>

#define BROWS  4096
#define NROWS  8192
#define D      256
#define NBLK   256   // persistent blocks == CUs; 1 block/CU (128 KB LDS)

typedef __attribute__((ext_vector_type(8))) short bf16x8;
typedef __attribute__((ext_vector_type(4))) float floatx4;

// LDS layout for A/B tiles (128 rows x 256 K, bf16):
//   index = ((cg*4 + cl)*128 + r) * 8 shorts, cg=k/32, cl=(k%32)/8
// Fragment read (lane lm,lg; K-iter kk): ((kk*4+lg)*128 + row)*8 -> 16 B stride
// across lm lanes = conflict-free (R2-verified pattern).

__global__ __launch_bounds__(256) void fused_contrast_kernel(
    const float* __restrict__ xi, const float* __restrict__ xj,
    short* __restrict__ z, float* __restrict__ pos,
    float* __restrict__ selfdot, float* __restrict__ rowsum,
    unsigned int* __restrict__ bar, unsigned int* __restrict__ done,
    float* __restrict__ out)
{
    __shared__ __align__(16) short A_lds[32768];   // 64 KB
    __shared__ __align__(16) short B_lds[32768];   // 64 KB
    __shared__ float sred[4];
    __shared__ unsigned int dcount;

    const int tid  = threadIdx.x;
    const int lane = tid & 63;
    const int w    = tid >> 6;     // wave 0..3
    const int lm   = lane & 15;
    const int lg   = lane >> 4;
    const int b    = blockIdx.x;

    // ---------------- phase 0: normalize + pos/selfdot + rowsum init ------
#pragma unroll
    for (int i = 0; i < 4; i++) {
        int p = b * 16 + w * 4 + i;
        float4 v1 = ((const float4*)(xi + (size_t)p * D))[lane];
        float4 v2 = ((const float4*)(xj + (size_t)p * D))[lane];
        float ss1 = v1.x * v1.x + v1.y * v1.y + v1.z * v1.z + v1.w * v1.w;
        float ss2 = v2.x * v2.x + v2.y * v2.y + v2.z * v2.z + v2.w * v2.w;
#pragma unroll
        for (int off = 32; off > 0; off >>= 1) {
            ss1 += __shfl_xor(ss1, off);
            ss2 += __shfl_xor(ss2, off);
        }
        float sc1 = 1.0f / fmaxf(sqrtf(ss1), 1e-12f);
        float sc2 = 1.0f / fmaxf(sqrtf(ss2), 1e-12f);
        union { __hip_bfloat16 h[4]; short4 s4; } u1, u2;
        u1.h[0] = __float2bfloat16(v1.x * sc1); u1.h[1] = __float2bfloat16(v1.y * sc1);
        u1.h[2] = __float2bfloat16(v1.z * sc1); u1.h[3] = __float2bfloat16(v1.w * sc1);
        u2.h[0] = __float2bfloat16(v2.x * sc2); u2.h[1] = __float2bfloat16(v2.y * sc2);
        u2.h[2] = __float2bfloat16(v2.z * sc2); u2.h[3] = __float2bfloat16(v2.w * sc2);
        ((short4*)(z + (size_t)p * D))[lane]           = u1.s4;
        ((short4*)(z + (size_t)(p + BROWS) * D))[lane] = u2.s4;
        float sd1 = 0.f, sd2 = 0.f, dp = 0.f;
#pragma unroll
        for (int j = 0; j < 4; j++) {
            float a = __bfloat162float(u1.h[j]);
            float bb = __bfloat162float(u2.h[j]);
            sd1 += a * a; sd2 += bb * bb; dp += a * bb;
        }
#pragma unroll
        for (int off = 32; off > 0; off >>= 1) {
            sd1 += __shfl_xor(sd1, off);
            sd2 += __shfl_xor(sd2, off);
            dp  += __shfl_xor(dp,  off);
        }
        if (lane == 0) {
            pos[p] = dp; pos[p + BROWS] = dp;
            selfdot[p] = sd1; selfdot[p + BROWS] = sd2;
        }
    }
    if (tid < 32) rowsum[b * 32 + tid] = 0.f;

    // ---------------- grid barrier (all 256 blocks co-resident) ----------
    __threadfence();
    __syncthreads();
    if (tid == 0) {
        __hip_atomic_fetch_add(bar, 1u, __ATOMIC_ACQ_REL, __HIP_MEMORY_SCOPE_AGENT);
        while (__hip_atomic_load(bar, __ATOMIC_RELAXED,
                                 __HIP_MEMORY_SCOPE_AGENT) < NBLK) { }
    }
    __syncthreads();
    __threadfence();   // acquire: z/pos/selfdot/rowsum from all blocks visible

    // ---------------- phase 1: symmetric 128x128 tiles --------------------
    // super-strip s = b>>3 pairs strips t0=s, t1=63-s (65 tiles); q = b&7.
    const int s  = b >> 3;
    const int q  = b & 7;
    const int t0 = s, t1 = 63 - s;
    const int L0 = 64 - t0;
    const int cb = (q * 65) >> 3;
    const int ce = ((q + 1) * 65) >> 3;

    const int srow = lane >> 2;   // staging: 16 rows / 4 k-slots per instr
    const int scl  = lane & 3;
    const int wr   = (w & 1) * 64;   // wave tile 64x64
    const int wc   = (w >> 1) * 64;

    bf16x8 breg[16];
    int cur_ti = -1;

    for (int c = cb; c < ce; c++) {
        int ti, tj;
        if (c < L0) { ti = t0; tj = t0 + c; }
        else        { ti = t1; tj = t1 + (c - L0); }
        const int m0 = ti * 128, n0 = tj * 128;
        const bool diag = (ti == tj);

        if (c == cb) {
            // synchronous first stage of A and B
            bf16x8 areg[16];
#pragma unroll
            for (int t = 0; t < 16; t++) {
                int cg = t & 7, rr = w * 32 + (t >> 3) * 16 + srow;
                areg[t] = *(const bf16x8*)(z + (size_t)(m0 + rr) * D + cg * 32 + scl * 8);
                breg[t] = *(const bf16x8*)(z + (size_t)(n0 + rr) * D + cg * 32 + scl * 8);
            }
#pragma unroll
            for (int t = 0; t < 16; t++) {
                int cg = t & 7, rr = w * 32 + (t >> 3) * 16 + srow;
                int idx = (((cg << 2) + scl) * 128 + rr) * 8;
                *(bf16x8*)(&A_lds[idx]) = areg[t];
                *(bf16x8*)(&B_lds[idx]) = breg[t];
            }
            cur_ti = ti;
            __syncthreads();
        }

        // prefetch next tile's B into registers (survives barriers; latency
        // hidden behind this tile's compute)
        const bool havenext = (c + 1 < ce);
        int nti = ti;
        if (havenext) {
            int cn = c + 1, ntj;
            if (cn < L0) { nti = t0; ntj = t0 + cn; }
            else         { nti = t1; ntj = t1 + (cn - L0); }
            const int nn0 = ntj * 128;
#pragma unroll
            for (int t = 0; t < 16; t++) {
                int cg = t & 7, rr = w * 32 + (t >> 3) * 16 + srow;
                breg[t] = *(const bf16x8*)(z + (size_t)(nn0 + rr) * D + cg * 32 + scl * 8);
            }
        }

        // ---- barrier-free K-loop: pure ds_read + MFMA ----
        floatx4 acc[4][4];
#pragma unroll
        for (int mi = 0; mi < 4; mi++)
#pragma unroll
            for (int ni = 0; ni < 4; ni++)
                acc[mi][ni] = (floatx4){0.f, 0.f, 0.f, 0.f};

#pragma unroll
        for (int kk = 0; kk < 8; kk++) {
            bf16x8 af[4], bfr[4];
#pragma unroll
            for (int mi = 0; mi < 4; mi++)
                af[mi] = *(const bf16x8*)(
                    &A_lds[(((kk << 2) + lg) * 128 + wr + mi * 16 + lm) * 8]);
#pragma unroll
            for (int ni = 0; ni < 4; ni++)
                bfr[ni] = *(const bf16x8*)(
                    &B_lds[(((kk << 2) + lg) * 128 + wc + ni * 16 + lm) * 8]);
#pragma unroll
            for (int mi = 0; mi < 4; mi++)
#pragma unroll
                for (int ni = 0; ni < 4; ni++)
                    acc[mi][ni] = __builtin_amdgcn_mfma_f32_16x16x32_bf16(
                        af[mi], bfr[ni], acc[mi][ni], 0, 0, 0);
        }

        // ---- epilogue: exp(2*sim), row/col partial sums, global atomics ----
        float rs[4][4], cs[4];
#pragma unroll
        for (int mi = 0; mi < 4; mi++)
#pragma unroll
            for (int r = 0; r < 4; r++) rs[mi][r] = 0.f;
#pragma unroll
        for (int ni = 0; ni < 4; ni++) cs[ni] = 0.f;
#pragma unroll
        for (int mi = 0; mi < 4; mi++)
#pragma unroll
            for (int ni = 0; ni < 4; ni++)
#pragma unroll
                for (int r = 0; r < 4; r++) {
                    float e = __expf(2.0f * acc[mi][ni][r]);
                    rs[mi][r] += e;
                    cs[ni]    += e;
                }
#pragma unroll
        for (int mi = 0; mi < 4; mi++)
#pragma unroll
            for (int r = 0; r < 4; r++) {
                float v = rs[mi][r];
                v += __shfl_xor(v, 1); v += __shfl_xor(v, 2);
                v += __shfl_xor(v, 4); v += __shfl_xor(v, 8);
                if (lm == 0)
                    atomicAdd(&rowsum[m0 + wr + mi * 16 + lg * 4 + r], v);
            }
        if (!diag) {
#pragma unroll
            for (int ni = 0; ni < 4; ni++) {
                float v = cs[ni];
                v += __shfl_xor(v, 16); v += __shfl_xor(v, 32);
                if (lane < 16)
                    atomicAdd(&rowsum[n0 + wc + ni * 16 + lm], v);
            }
        }

        __syncthreads();   // all waves done reading B_lds (and A_lds)

        if (havenext) {
            if (nti != cur_ti) {   // strip change: restage A (≤1x per block)
                bf16x8 areg[16];
                const int nm0 = nti * 128;
#pragma unroll
                for (int t = 0; t < 16; t++) {
                    int cg = t & 7, rr = w * 32 + (t >> 3) * 16 + srow;
                    areg[t] = *(const bf16x8*)(z + (size_t)(nm0 + rr) * D + cg * 32 + scl * 8);
                }
#pragma unroll
                for (int t = 0; t < 16; t++) {
                    int cg = t & 7, rr = w * 32 + (t >> 3) * 16 + srow;
                    *(bf16x8*)(&A_lds[(((cg << 2) + scl) * 128 + rr) * 8]) = areg[t];
                }
                cur_ti = nti;
            }
#pragma unroll
            for (int t = 0; t < 16; t++) {
                int cg = t & 7, rr = w * 32 + (t >> 3) * 16 + srow;
                *(bf16x8*)(&B_lds[(((cg << 2) + scl) * 128 + rr) * 8]) = breg[t];
            }
            __syncthreads();   // staged data visible before next compute
        }
    }

    // ---------------- loss tail: last finished block ----------------------
    __threadfence();
    __syncthreads();
    if (tid == 0)
        dcount = __hip_atomic_fetch_add(done, 1u, __ATOMIC_ACQ_REL,
                                        __HIP_MEMORY_SCOPE_AGENT);
    __syncthreads();
    if (dcount == NBLK - 1) {
        __threadfence();
        float acc_l = 0.f;
#pragma unroll 4
        for (int r = tid; r < NROWS; r += 256) {
            float rsv = __hip_atomic_load(&rowsum[r], __ATOMIC_RELAXED,
                                          __HIP_MEMORY_SCOPE_AGENT);
            float pv  = __hip_atomic_load(&pos[r], __ATOMIC_RELAXED,
                                          __HIP_MEMORY_SCOPE_AGENT);
            float sv  = __hip_atomic_load(&selfdot[r], __ATOMIC_RELAXED,
                                          __HIP_MEMORY_SCOPE_AGENT);
            acc_l += -2.0f * pv + logf(rsv - __expf(2.0f * sv));
        }
#pragma unroll
        for (int off = 32; off > 0; off >>= 1) acc_l += __shfl_xor(acc_l, off);
        if (lane == 0) sred[w] = acc_l;
        __syncthreads();
        if (tid == 0)
            out[0] = (sred[0] + sred[1] + sred[2] + sred[3]) / (float)NROWS;
    }
}

// ---------------------------------------------------------------------------
extern "C" void kernel_launch(void* const* d_in, const int* in_sizes, int n_in,
                              void* d_out, int out_size, void* d_ws, size_t ws_size,
                              hipStream_t stream) {
    const float* xi = (const float*)d_in[0];
    const float* xj = (const float*)d_in[1];
    float* out      = (float*)d_out;

    char* ws        = (char*)d_ws;
    short* z        = (short*)ws;                             // 4 MiB
    float* rowsum   = (float*)(ws + (size_t)NROWS * D * 2);   // 32 KiB
    float* pos      = rowsum + NROWS;                         // 32 KiB
    float* selfdot  = pos + NROWS;                            // 32 KiB
    unsigned int* counters = (unsigned int*)(selfdot + NROWS); // bar, done

    hipMemsetAsync(counters, 0, 2 * sizeof(unsigned int), stream);
    fused_contrast_kernel<<<NBLK, 256, 0, stream>>>(
        xi, xj, z, pos, selfdot, rowsum, counters, counters + 1, out);
}

// Round 6
// 135.562 us; speedup vs baseline: 1.4191x; 1.4191x over previous
//
#include <hip/hip_runtime.h>
#include <hip/hip_bf16.h>

#define B_ROWS 4096
#define NROWS  8192   // 2B
#define D      256
#define TILES  64     // NROWS / 128
#define NPAIRS 2080   // TILES*(TILES+1)/2 upper-triangular tile pairs

typedef __attribute__((ext_vector_type(8))) short bf16x8;
typedef __attribute__((ext_vector_type(4))) float floatx4;

// LDS slab layout (per 128-row x 32-K slab), in 16-byte units:
//   u(row, chunk) = row*4 + (chunk ^ ((row>>2)&3)),  chunk = k16 index 0..3
// Properties (bank-enumerated):
//   fetch: lanes (srow=lane>>2, scl=lane&3) read row srow chunk scl -> 4 lanes
//          cover one fully-consumed 64B line; 16 lines/instr (coalesced).
//   ds_write_b128: u covers 64 consecutive units -> lane-dense, conflict-free.
//   ds_read_b128 frag (row=base+lm, chunk=lg): every 4-bank group hit by
//          exactly 8 lanes over 8 phases -> conflict-free (2-way, free).

// ---------------------------------------------------------------------------
// Kernel 1: fused normalize + pos + selfdot + zero-init rowsum/out/counter.
// ---------------------------------------------------------------------------
__global__ __launch_bounds__(256) void norm_pos_kernel(
    const float* __restrict__ xi, const float* __restrict__ xj,
    short* __restrict__ z, float* __restrict__ pos,
    float* __restrict__ selfdot, float* __restrict__ rowsum,
    float* __restrict__ out, unsigned int* __restrict__ counter) {
    int gt = blockIdx.x * 256 + threadIdx.x;
    if (gt < NROWS) rowsum[gt] = 0.f;
    if (gt == 0) { out[0] = 0.f; counter[0] = 0u; }

    int p    = blockIdx.x * 4 + (threadIdx.x >> 6);
    int lane = threadIdx.x & 63;
    float4 v1 = ((const float4*)(xi + (size_t)p * D))[lane];
    float4 v2 = ((const float4*)(xj + (size_t)p * D))[lane];
    float ss1 = v1.x * v1.x + v1.y * v1.y + v1.z * v1.z + v1.w * v1.w;
    float ss2 = v2.x * v2.x + v2.y * v2.y + v2.z * v2.z + v2.w * v2.w;
#pragma unroll
    for (int off = 32; off > 0; off >>= 1) {
        ss1 += __shfl_xor(ss1, off);
        ss2 += __shfl_xor(ss2, off);
    }
    float sc1 = 1.0f / fmaxf(sqrtf(ss1), 1e-12f);
    float sc2 = 1.0f / fmaxf(sqrtf(ss2), 1e-12f);

    union { __hip_bfloat16 h[4]; short4 s4; } u1, u2;
    u1.h[0] = __float2bfloat16(v1.x * sc1); u1.h[1] = __float2bfloat16(v1.y * sc1);
    u1.h[2] = __float2bfloat16(v1.z * sc1); u1.h[3] = __float2bfloat16(v1.w * sc1);
    u2.h[0] = __float2bfloat16(v2.x * sc2); u2.h[1] = __float2bfloat16(v2.y * sc2);
    u2.h[2] = __float2bfloat16(v2.z * sc2); u2.h[3] = __float2bfloat16(v2.w * sc2);
    ((short4*)(z + (size_t)p * D))[lane]            = u1.s4;
    ((short4*)(z + (size_t)(p + B_ROWS) * D))[lane] = u2.s4;

    float sd1 = 0.f, sd2 = 0.f, dp = 0.f;
#pragma unroll
    for (int j = 0; j < 4; j++) {
        float a = __bfloat162float(u1.h[j]);
        float b = __bfloat162float(u2.h[j]);
        sd1 += a * a; sd2 += b * b; dp += a * b;
    }
#pragma unroll
    for (int off = 32; off > 0; off >>= 1) {
        sd1 += __shfl_xor(sd1, off);
        sd2 += __shfl_xor(sd2, off);
        dp  += __shfl_xor(dp,  off);
    }
    if (lane == 0) {
        pos[p] = dp; pos[p + B_ROWS] = dp;
        selfdot[p] = sd1; selfdot[p + B_ROWS] = sd2;
    }
}

// ---------------------------------------------------------------------------
// Kernel 2: symmetric fused sim+exp+rowsum (+ last-block loss tail).
// 128x128 tiles, 4 waves, wave tile 64x64. Double-buffered K32 rounds with
// swizzled LDS, explicit VGPR staging, ONE barrier per round.
// ---------------------------------------------------------------------------
__global__ __launch_bounds__(256) void sim_rowsum_kernel(
    const short* __restrict__ z, float* __restrict__ rowsum,
    const float* __restrict__ pos, const float* __restrict__ selfdot,
    unsigned int* __restrict__ counter, float* __restrict__ out) {
    __shared__ __align__(16) short A_lds[2][4096];   // 8 KB per buf
    __shared__ __align__(16) short B_lds[2][4096];
    __shared__ float rs_lds[128];
    __shared__ float cs_lds[128];
    __shared__ unsigned int done_s;
    __shared__ float sdata[4];

    const int tid  = threadIdx.x;
    const int lane = tid & 63;
    const int w    = tid >> 6;
    const int lm   = lane & 15;
    const int lg   = lane >> 4;

    // decode upper-triangular tile pair (ti <= tj)
    int bid = blockIdx.x;
    int ti  = (int)((129.0 - sqrt(16641.0 - 8.0 * (double)bid)) * 0.5);
    while (ti > 0 && ti * TILES - ti * (ti - 1) / 2 > bid) ti--;
    while ((ti + 1) * TILES - (ti + 1) * ti / 2 <= bid) ti++;
    int tj = ti + (bid - (ti * TILES - ti * (ti - 1) / 2));
    const int m0 = ti * 128, n0 = tj * 128;

    const int wr = (w & 1) * 64;
    const int wc = (w >> 1) * 64;

    if (tid < 128) { rs_lds[tid] = 0.f; cs_lds[tid] = 0.f; }

    // staging geometry: this thread covers (row = srow16h + lane>>2, chunk scl)
    const int srow = lane >> 2;          // 0..15
    const int scl  = lane & 3;
    // two stage instrs per thread per array: h=0 -> rows w*32.., h=1 -> +16
    int srw[2];                          // local rows staged
    int sui[2];                          // LDS 16B-unit index (swizzled)
#pragma unroll
    for (int h = 0; h < 2; h++) {
        int r  = w * 32 + h * 16 + srow;
        srw[h] = r;
        sui[h] = (r * 4 + (scl ^ ((r >> 2) & 3))) * 8;   // short index
    }
    const short* agp[2];
    const short* bgp[2];
#pragma unroll
    for (int h = 0; h < 2; h++) {
        agp[h] = z + (size_t)(m0 + srw[h]) * D + scl * 8;
        bgp[h] = z + (size_t)(n0 + srw[h]) * D + scl * 8;
    }

    // fragment read indices (current-slab relative, short units)
    int fai[4], fbi[4];
#pragma unroll
    for (int mi = 0; mi < 4; mi++) {
        int r = wr + mi * 16 + lm;
        fai[mi] = (r * 4 + (lg ^ ((lm >> 2) & 3))) * 8;
    }
#pragma unroll
    for (int ni = 0; ni < 4; ni++) {
        int r = wc + ni * 16 + lm;
        fbi[ni] = (r * 4 + (lg ^ ((lm >> 2) & 3))) * 8;
    }

    floatx4 acc[4][4];
#pragma unroll
    for (int mi = 0; mi < 4; mi++)
#pragma unroll
        for (int ni = 0; ni < 4; ni++) acc[mi][ni] = (floatx4){0.f, 0.f, 0.f, 0.f};

    // prologue: stage slab 0 into buffer 0
    bf16x8 ar[2], br[2];
#pragma unroll
    for (int h = 0; h < 2; h++) {
        ar[h] = *(const bf16x8*)(agp[h]);
        br[h] = *(const bf16x8*)(bgp[h]);
    }
#pragma unroll
    for (int h = 0; h < 2; h++) {
        *(bf16x8*)(&A_lds[0][sui[h]]) = ar[h];
        *(bf16x8*)(&B_lds[0][sui[h]]) = br[h];
    }
    __syncthreads();

#pragma unroll
    for (int it = 0; it < 8; it++) {
        const int cur = it & 1;
        // prefetch next slab into VGPRs (latency hides behind MFMAs below)
        if (it < 7) {
            int ko = (it + 1) * 32;      // shorts
#pragma unroll
            for (int h = 0; h < 2; h++) {
                ar[h] = *(const bf16x8*)(agp[h] + ko);
                br[h] = *(const bf16x8*)(bgp[h] + ko);
            }
        }

        bf16x8 af[4], bfr[4];
#pragma unroll
        for (int mi = 0; mi < 4; mi++)
            af[mi] = *(const bf16x8*)(&A_lds[cur][fai[mi]]);
#pragma unroll
        for (int ni = 0; ni < 4; ni++)
            bfr[ni] = *(const bf16x8*)(&B_lds[cur][fbi[ni]]);
#pragma unroll
        for (int mi = 0; mi < 4; mi++)
#pragma unroll
            for (int ni = 0; ni < 4; ni++)
                acc[mi][ni] = __builtin_amdgcn_mfma_f32_16x16x32_bf16(
                    af[mi], bfr[ni], acc[mi][ni], 0, 0, 0);

        if (it < 7) {
            // write next slab into the buffer last read in round it-1
#pragma unroll
            for (int h = 0; h < 2; h++) {
                *(bf16x8*)(&A_lds[cur ^ 1][sui[h]]) = ar[h];
                *(bf16x8*)(&B_lds[cur ^ 1][sui[h]]) = br[h];
            }
            __syncthreads();   // one barrier per round
        }
    }

    // ---- epilogue: e = exp(2*sim); row partials + (offdiag) col partials ----
    float rs[4][4], cs[4];
#pragma unroll
    for (int mi = 0; mi < 4; mi++)
#pragma unroll
        for (int r = 0; r < 4; r++) rs[mi][r] = 0.f;
#pragma unroll
    for (int ni = 0; ni < 4; ni++) cs[ni] = 0.f;

#pragma unroll
    for (int mi = 0; mi < 4; mi++)
#pragma unroll
        for (int ni = 0; ni < 4; ni++)
#pragma unroll
            for (int r = 0; r < 4; r++) {
                float e = __expf(2.0f * acc[mi][ni][r]);
                rs[mi][r] += e;
                cs[ni]    += e;
            }

    const bool offdiag = (ti != tj);
#pragma unroll
    for (int mi = 0; mi < 4; mi++)
#pragma unroll
        for (int r = 0; r < 4; r++) {
            float s = rs[mi][r];
            s += __shfl_xor(s, 1); s += __shfl_xor(s, 2);
            s += __shfl_xor(s, 4); s += __shfl_xor(s, 8);
            if (lm == 0) atomicAdd(&rs_lds[wr + mi * 16 + lg * 4 + r], s);
        }
    if (offdiag) {
#pragma unroll
        for (int ni = 0; ni < 4; ni++) {
            float s = cs[ni];
            s += __shfl_xor(s, 16); s += __shfl_xor(s, 32);
            if (lane < 16) atomicAdd(&cs_lds[wc + ni * 16 + lm], s);
        }
    }
    __syncthreads();
    if (tid < 128) {
        atomicAdd(&rowsum[m0 + tid], rs_lds[tid]);
    } else if (offdiag) {
        atomicAdd(&rowsum[n0 + tid - 128], cs_lds[tid - 128]);
    }

    // ---- last-block-done: final loss ----
    __syncthreads();
    if (tid == 0) {
        __threadfence();
        done_s = atomicAdd(counter, 1u);
    }
    __syncthreads();
    if (done_s == (unsigned int)(NPAIRS - 1)) {
        __threadfence();
        float acc_l = 0.f;
#pragma unroll 4
        for (int r = tid; r < NROWS; r += 256) {
            float rsv = __hip_atomic_load(&rowsum[r], __ATOMIC_RELAXED,
                                          __HIP_MEMORY_SCOPE_AGENT);
            float denom = rsv - __expf(2.0f * selfdot[r]);
            acc_l += -2.0f * pos[r] + logf(denom);
        }
#pragma unroll
        for (int off = 32; off > 0; off >>= 1) acc_l += __shfl_xor(acc_l, off);
        if (lane == 0) sdata[w] = acc_l;
        __syncthreads();
        if (tid == 0)
            out[0] = (sdata[0] + sdata[1] + sdata[2] + sdata[3]) / (float)NROWS;
    }
}

// ---------------------------------------------------------------------------
extern "C" void kernel_launch(void* const* d_in, const int* in_sizes, int n_in,
                              void* d_out, int out_size, void* d_ws, size_t ws_size,
                              hipStream_t stream) {
    const float* xi = (const float*)d_in[0];
    const float* xj = (const float*)d_in[1];
    float* out      = (float*)d_out;

    char* ws        = (char*)d_ws;
    short* z        = (short*)ws;                             // 4 MiB
    float* rowsum   = (float*)(ws + (size_t)NROWS * D * 2);   // 32 KiB
    float* pos      = rowsum + NROWS;                         // 32 KiB
    float* selfdot  = pos + NROWS;                            // 32 KiB
    unsigned int* counter = (unsigned int*)(selfdot + NROWS);

    norm_pos_kernel<<<B_ROWS / 4, 256, 0, stream>>>(xi, xj, z, pos, selfdot,
                                                    rowsum, out, counter);
    sim_rowsum_kernel<<<NPAIRS, 256, 0, stream>>>(z, rowsum, pos, selfdot,
                                                  counter, out);
}

// Round 7
// 99.837 us; speedup vs baseline: 1.9270x; 1.3578x over previous
//
#include <hip/hip_runtime.h>
#include <hip/hip_bf16.h>

#define B_ROWS 4096
#define NROWS  8192   // 2B
#define D      256
#define NPANEL 32     // 256-row panels
#define NSEG   32     // segments per strip-pair
#define NBLK2  512    // 16 pairs * 32 segments
#define TT     264    // tiles per strip-pair (32-col tiles)

typedef __attribute__((ext_vector_type(8))) short bf16x8;
typedef __attribute__((ext_vector_type(4))) float floatx4;

// ---------------------------------------------------------------------------
// Kernel 1: fused normalize + pos + selfdot + zero-init rowsum/out/counter.
// ---------------------------------------------------------------------------
__global__ __launch_bounds__(256) void norm_pos_kernel(
    const float* __restrict__ xi, const float* __restrict__ xj,
    short* __restrict__ z, float* __restrict__ pos,
    float* __restrict__ selfdot, float* __restrict__ rowsum,
    float* __restrict__ out, unsigned int* __restrict__ counter) {
    int gt = blockIdx.x * 256 + threadIdx.x;
    if (gt < NROWS) rowsum[gt] = 0.f;
    if (gt == 0) { out[0] = 0.f; counter[0] = 0u; }

    int p    = blockIdx.x * 4 + (threadIdx.x >> 6);
    int lane = threadIdx.x & 63;
    float4 v1 = ((const float4*)(xi + (size_t)p * D))[lane];
    float4 v2 = ((const float4*)(xj + (size_t)p * D))[lane];
    float ss1 = v1.x * v1.x + v1.y * v1.y + v1.z * v1.z + v1.w * v1.w;
    float ss2 = v2.x * v2.x + v2.y * v2.y + v2.z * v2.z + v2.w * v2.w;
#pragma unroll
    for (int off = 32; off > 0; off >>= 1) {
        ss1 += __shfl_xor(ss1, off);
        ss2 += __shfl_xor(ss2, off);
    }
    float sc1 = 1.0f / fmaxf(sqrtf(ss1), 1e-12f);
    float sc2 = 1.0f / fmaxf(sqrtf(ss2), 1e-12f);

    union { __hip_bfloat16 h[4]; short4 s4; } u1, u2;
    u1.h[0] = __float2bfloat16(v1.x * sc1); u1.h[1] = __float2bfloat16(v1.y * sc1);
    u1.h[2] = __float2bfloat16(v1.z * sc1); u1.h[3] = __float2bfloat16(v1.w * sc1);
    u2.h[0] = __float2bfloat16(v2.x * sc2); u2.h[1] = __float2bfloat16(v2.y * sc2);
    u2.h[2] = __float2bfloat16(v2.z * sc2); u2.h[3] = __float2bfloat16(v2.w * sc2);
    ((short4*)(z + (size_t)p * D))[lane]            = u1.s4;
    ((short4*)(z + (size_t)(p + B_ROWS) * D))[lane] = u2.s4;

    float sd1 = 0.f, sd2 = 0.f, dp = 0.f;
#pragma unroll
    for (int j = 0; j < 4; j++) {
        float a = __bfloat162float(u1.h[j]);
        float b = __bfloat162float(u2.h[j]);
        sd1 += a * a; sd2 += b * b; dp += a * b;
    }
#pragma unroll
    for (int off = 32; off > 0; off >>= 1) {
        sd1 += __shfl_xor(sd1, off);
        sd2 += __shfl_xor(sd2, off);
        dp  += __shfl_xor(dp,  off);
    }
    if (lane == 0) {
        pos[p] = dp; pos[p + B_ROWS] = dp;
        selfdot[p] = sd1; selfdot[p + B_ROWS] = sd2;
    }
}

// ---------------------------------------------------------------------------
// Kernel 2: symmetric sim+exp+rowsum, register-resident A panels.
// Strip-pair schedule: pair s pairs panel s (rows 256s..) with panel 31-s;
// strip of panel p = upper-tri cols [256p, 8192) in 32-col tiles
// (256-8p tiles), pair total = 264 tiles, split over 32 segment-blocks.
// Wave holds A = 64 rows x 256 K in 128 VGPRs (a[kk][mi]); B tiles (32 cols
// x 256 K = 16 KB) double-buffered in LDS, swizzle u(col,c)=col*32+(c^(col&7))
// (16B units): coalesced fetch, conflict-free ds_write_b128 + ds_read_b128.
// 64 MFMAs per wave between barriers; row sums accumulate in registers;
// mirror (col-side) sums only for tiles past the 256-diag block.
// ---------------------------------------------------------------------------
__global__ __launch_bounds__(256, 2) void sim_rowsum_kernel(
    const short* __restrict__ z, float* __restrict__ rowsum,
    const float* __restrict__ pos, const float* __restrict__ selfdot,
    unsigned int* __restrict__ counter, float* __restrict__ out) {
    __shared__ __align__(16) short Bbuf[2][8192];   // 2 x 16 KB
    __shared__ unsigned int done_s;
    __shared__ float sdata[4];

    const int tid  = threadIdx.x;
    const int lane = tid & 63;
    const int w    = tid >> 6;
    const int lm   = lane & 15;
    const int lg   = lane >> 4;

    const int s  = blockIdx.x >> 5;     // strip-pair 0..15
    const int q  = blockIdx.x & 31;     // segment
    const int L0 = 256 - 8 * s;         // tiles in first strip (panel s)
    const int cb = (q * TT) >> 5;
    const int ce = ((q + 1) * TT) >> 5;

    // staging geometry
    const int scol = tid >> 3;          // 0..31
    const int sg   = tid & 7;
    const int sxor = scol & 7;

    // fragment-read xor term
    const int fxor = lm & 7;

    bf16x8 a[8][4];                     // A panel: 64 rows x 256 K (128 VGPRs)
    floatx4 acc[4][2];
    float rsacc[4][4];
    bf16x8 pf[4];

#pragma unroll
    for (int mi = 0; mi < 4; mi++)
#pragma unroll
        for (int r = 0; r < 4; r++) rsacc[mi][r] = 0.f;

    // ---- decode tile c -> (panel, colbase, mirror) ----
    auto decode = [&](int c, int& panel, int& colbase, bool& mirror) {
        int cloc;
        if (c < L0) { panel = s;      cloc = c; }
        else        { panel = 31 - s; cloc = c - L0; }
        colbase = panel * 256 + cloc * 32;
        mirror  = (cloc >= 8);
    };

    auto loadA = [&](int panel) {
#pragma unroll
        for (int kk = 0; kk < 8; kk++)
#pragma unroll
            for (int mi = 0; mi < 4; mi++)
                a[kk][mi] = *(const bf16x8*)(
                    z + (size_t)(panel * 256 + w * 64 + mi * 16 + lm) * D +
                    kk * 32 + lg * 8);
    };

    auto flushRs = [&](int panel) {
#pragma unroll
        for (int mi = 0; mi < 4; mi++)
#pragma unroll
            for (int r = 0; r < 4; r++) {
                float v = rsacc[mi][r];
                v += __shfl_xor(v, 1); v += __shfl_xor(v, 2);
                v += __shfl_xor(v, 4); v += __shfl_xor(v, 8);
                if (lm == 0)
                    atomicAdd(&rowsum[panel * 256 + w * 64 + mi * 16 + lg * 4 + r], v);
                rsacc[mi][r] = 0.f;
            }
    };

    auto fetch = [&](int colbase) {
        const short* p = z + (size_t)(colbase + scol) * D + sg * 8;
#pragma unroll
        for (int j = 0; j < 4; j++) pf[j] = *(const bf16x8*)(p + j * 64);
    };
    auto writeB = [&](int buf) {
#pragma unroll
        for (int j = 0; j < 4; j++) {
            int u = scol * 32 + ((sg + 8 * j) ^ sxor);
            *(bf16x8*)(&Bbuf[buf][u * 8]) = pf[j];
        }
    };

    // ---- prologue: stage first tile, load A panel ----
    int panel, colbase; bool mirror;
    decode(cb, panel, colbase, mirror);
    int curpanel = panel;
    fetch(colbase);
    writeB(0);
    loadA(panel);
    __syncthreads();

    for (int c = cb; c < ce; c++) {
        const int buf = (c - cb) & 1;
        decode(c, panel, colbase, mirror);

        const bool hn = (c + 1 < ce);
        if (hn) {
            int npanel, ncolbase; bool nm;
            decode(c + 1, npanel, ncolbase, nm);
            fetch(ncolbase);
        }
        if (panel != curpanel) {      // strip change (≤1 per block)
            flushRs(curpanel);
            loadA(panel);
            curpanel = panel;
        }

#pragma unroll
        for (int mi = 0; mi < 4; mi++)
#pragma unroll
            for (int ni = 0; ni < 2; ni++)
                acc[mi][ni] = (floatx4){0.f, 0.f, 0.f, 0.f};

#pragma unroll
        for (int kk = 0; kk < 8; kk++) {
            bf16x8 b0 = *(const bf16x8*)(
                &Bbuf[buf][(( (0 * 16 + lm) * 32) + ((kk * 4 + lg) ^ fxor)) * 8]);
            bf16x8 b1 = *(const bf16x8*)(
                &Bbuf[buf][(( (1 * 16 + lm) * 32) + ((kk * 4 + lg) ^ fxor)) * 8]);
#pragma unroll
            for (int mi = 0; mi < 4; mi++)
                acc[mi][0] = __builtin_amdgcn_mfma_f32_16x16x32_bf16(
                    a[kk][mi], b0, acc[mi][0], 0, 0, 0);
#pragma unroll
            for (int mi = 0; mi < 4; mi++)
                acc[mi][1] = __builtin_amdgcn_mfma_f32_16x16x32_bf16(
                    a[kk][mi], b1, acc[mi][1], 0, 0, 0);
        }

        // epilogue: exp(2*sim) -> register row-sums (+ mirror col-sums)
        float cs0 = 0.f, cs1 = 0.f;
#pragma unroll
        for (int mi = 0; mi < 4; mi++)
#pragma unroll
            for (int r = 0; r < 4; r++) {
                float e0 = __expf(2.0f * acc[mi][0][r]);
                float e1 = __expf(2.0f * acc[mi][1][r]);
                rsacc[mi][r] += e0 + e1;
                cs0 += e0; cs1 += e1;
            }
        if (mirror) {
            cs0 += __shfl_xor(cs0, 16); cs0 += __shfl_xor(cs0, 32);
            cs1 += __shfl_xor(cs1, 16); cs1 += __shfl_xor(cs1, 32);
            if (lane < 16) {
                atomicAdd(&rowsum[colbase + lane],      cs0);
                atomicAdd(&rowsum[colbase + 16 + lane], cs1);
            }
        }

        if (hn) {
            writeB(buf ^ 1);
            __syncthreads();
        }
    }
    flushRs(curpanel);

    // ---- last-block-done: final loss ----
    __syncthreads();
    if (tid == 0) {
        __threadfence();
        done_s = atomicAdd(counter, 1u);
    }
    __syncthreads();
    if (done_s == (unsigned int)(NBLK2 - 1)) {
        __threadfence();
        float acc_l = 0.f;
#pragma unroll 4
        for (int r = tid; r < NROWS; r += 256) {
            float rsv = __hip_atomic_load(&rowsum[r], __ATOMIC_RELAXED,
                                          __HIP_MEMORY_SCOPE_AGENT);
            float denom = rsv - __expf(2.0f * selfdot[r]);
            acc_l += -2.0f * pos[r] + logf(denom);
        }
#pragma unroll
        for (int off = 32; off > 0; off >>= 1) acc_l += __shfl_xor(acc_l, off);
        if (lane == 0) sdata[w] = acc_l;
        __syncthreads();
        if (tid == 0)
            out[0] = (sdata[0] + sdata[1] + sdata[2] + sdata[3]) / (float)NROWS;
    }
}

// ---------------------------------------------------------------------------
extern "C" void kernel_launch(void* const* d_in, const int* in_sizes, int n_in,
                              void* d_out, int out_size, void* d_ws, size_t ws_size,
                              hipStream_t stream) {
    const float* xi = (const float*)d_in[0];
    const float* xj = (const float*)d_in[1];
    float* out      = (float*)d_out;

    char* ws        = (char*)d_ws;
    short* z        = (short*)ws;                             // 4 MiB
    float* rowsum   = (float*)(ws + (size_t)NROWS * D * 2);   // 32 KiB
    float* pos      = rowsum + NROWS;                         // 32 KiB
    float* selfdot  = pos + NROWS;                            // 32 KiB
    unsigned int* counter = (unsigned int*)(selfdot + NROWS);

    norm_pos_kernel<<<B_ROWS / 4, 256, 0, stream>>>(xi, xj, z, pos, selfdot,
                                                    rowsum, out, counter);
    sim_rowsum_kernel<<<NBLK2, 256, 0, stream>>>(z, rowsum, pos, selfdot,
                                                 counter, out);
}